// Round 6
// baseline (980.954 us; speedup 1.0000x reference)
//
#include <hip/hip_runtime.h>

// Problem constants (fixed by reference)
#define NN 50000      // nodes
#define NE 800000     // edges
#define DD 256        // node feat dim
#define GFEAT 200     // graph feat dim
#define NG 512        // graphs
#define NBK 782       // dst buckets of 64 nodes

typedef __bf16 bf16;
typedef bf16 bf16x4 __attribute__((ext_vector_type(4)));
typedef bf16 bf16x8 __attribute__((ext_vector_type(8)));
typedef float f32x4 __attribute__((ext_vector_type(4)));

// async global->LDS, 16B per lane. HW dest = wave-uniform base + lane*16.
__device__ __forceinline__ void gl_lds16(const bf16* g, bf16* l) {
    __builtin_amdgcn_global_load_lds(
        (const __attribute__((address_space(1))) uint32_t*)(g),
        (__attribute__((address_space(3))) uint32_t*)(l), 16, 0, 0);
}

// swizzled fragment read: LDS [row][32k] where chunk c holds global chunk c^((row>>1)&3)
__device__ __forceinline__ bf16x8 frag_ld(const bf16* s, int R, int C) {
    return *(const bf16x8*)&s[R * 32 + ((C ^ ((R >> 1) & 3)) << 3)];
}

#define EPI_STRIDE 136   // bf16 elems; 272 B row stride (16B-aligned, bank-shift 4/row)

// ---------------------------------------------------------------------------
// conversions
// ---------------------------------------------------------------------------
__global__ __launch_bounds__(256) void conv_x2_kernel(const float* __restrict__ in0,
                                                      const float* __restrict__ in1,
                                                      bf16* __restrict__ out0,
                                                      bf16* __restrict__ out1, int n4) {
    const float* in = blockIdx.y ? in1 : in0;
    bf16* out = blockIdx.y ? out1 : out0;
    int i = blockIdx.x * 256 + threadIdx.x;
    if (i < n4) {
        float4 v = ((const float4*)in)[i];
        bf16x4 o;
        o[0] = (bf16)v.x; o[1] = (bf16)v.y; o[2] = (bf16)v.z; o[3] = (bf16)v.w;
        ((bf16x4*)out)[i] = o;
    }
}

// 8 weight matrices fp32 [K][N] -> bf16 [256][256] = [n][k] transposed, zero-padded.
__global__ __launch_bounds__(256) void conv_w8_kernel(
    const float* __restrict__ w0, const float* __restrict__ w1,
    const float* __restrict__ w2, const float* __restrict__ w3,
    const float* __restrict__ w4, const float* __restrict__ w5,
    const float* __restrict__ w6, const float* __restrict__ w7,
    bf16* __restrict__ out_base) {
    const float* ws[8] = {w0, w1, w2, w3, w4, w5, w6, w7};
    const int Ns[8] = {DD, DD, DD, GFEAT, DD, DD, DD, GFEAT};
    int m = blockIdx.y;
    const float* in = ws[m];
    int N = Ns[m];
    int idx = blockIdx.x * 256 + threadIdx.x;   // 0..65535 over [n][k]
    int n = idx >> 8, k = idx & 255;
    float v = (n < N) ? in[k * N + n] : 0.f;
    out_base[(size_t)m * 65536 + idx] = (bf16)v;
}

// ---------------------------------------------------------------------------
// bucketed CSR build (both branches batched via blockIdx.y)
// ---------------------------------------------------------------------------
__global__ __launch_bounds__(1024) void zero_small2_kernel(int* __restrict__ a,
                                                           int* __restrict__ b, int n) {
    int t = threadIdx.x;
    for (int i = t; i < n; i += 1024) { a[i] = 0; b[i] = 0; }
}

// per-block LDS histogram over NBK bucket counters; 2048 edges/block
__global__ __launch_bounds__(256) void bucket_hist2_kernel(const int* __restrict__ d0,
                                                           const int* __restrict__ d1,
                                                           int* __restrict__ c0,
                                                           int* __restrict__ c1, int n) {
    const int* dst = blockIdx.y ? d1 : d0;
    int* bcnt = blockIdx.y ? c1 : c0;
    __shared__ int cnt[NBK];
    int t = threadIdx.x;
    for (int i = t; i < NBK; i += 256) cnt[i] = 0;
    __syncthreads();
    int base = blockIdx.x * 2048;
#pragma unroll
    for (int r = 0; r < 8; r++) {
        int e = base + r * 256 + t;
        if (e < n) atomicAdd(&cnt[dst[e] >> 6], 1);
    }
    __syncthreads();
    for (int i = t; i < NBK; i += 256) if (cnt[i]) atomicAdd(&bcnt[i], cnt[i]);
}

// single-block scan of NBK bucket counts -> boffs (excl), bcur copy, totals
__global__ __launch_bounds__(1024) void bucket_scan2_kernel(
    const int* __restrict__ c0, const int* __restrict__ c1,
    int* __restrict__ bo0, int* __restrict__ bo1,
    int* __restrict__ bc0, int* __restrict__ bc1,
    int* __restrict__ offsN0, int* __restrict__ offsN1) {
    const int* bcnt = blockIdx.y ? c1 : c0;
    int* boffs = blockIdx.y ? bo1 : bo0;
    int* bcur  = blockIdx.y ? bc1 : bc0;
    int* offsN = blockIdx.y ? offsN1 : offsN0;   // &offs[NN]
    __shared__ int s[1024];
    int t = threadIdx.x;
    int x = (t < NBK) ? bcnt[t] : 0;
    s[t] = x;
    __syncthreads();
    for (int off = 1; off < 1024; off <<= 1) {
        int v = (t >= off) ? s[t - off] : 0;
        __syncthreads();
        s[t] += v;
        __syncthreads();
    }
    if (t < NBK) { boffs[t] = s[t] - x; bcur[t] = s[t] - x; }
    if (t == 1023) { boffs[NBK] = s[1023]; offsN[0] = s[1023]; }
}

// append packed (dl<<20)|src to bucket streams (sequential-in-time line fill)
__global__ __launch_bounds__(256) void bucket_append2_kernel(
    const int* __restrict__ s0, const int* __restrict__ s1,
    const int* __restrict__ d0, const int* __restrict__ d1,
    int* __restrict__ bc0, int* __restrict__ bc1,
    unsigned* __restrict__ pr0, unsigned* __restrict__ pr1, int n) {
    const int* src = blockIdx.y ? s1 : s0;
    const int* dst = blockIdx.y ? d1 : d0;
    int* bcur = blockIdx.y ? bc1 : bc0;
    unsigned* pairs = blockIdx.y ? pr1 : pr0;
    int e = blockIdx.x * 256 + threadIdx.x;
    if (e < n) {
        int dv = dst[e];
        int b = dv >> 6;
        int pos = atomicAdd(&bcur[b], 1);
        pairs[pos] = (unsigned)src[e] | ((unsigned)(dv & 63) << 20);
    }
}

// one WG per bucket: local counting sort of its pairs into its contiguous csr
// slice (single-CU, L2-local writes); also emits per-node offs.
__global__ __launch_bounds__(256) void fine_scatter2_kernel(
    const unsigned* __restrict__ pr0, const unsigned* __restrict__ pr1,
    const int* __restrict__ bo0, const int* __restrict__ bo1,
    int* __restrict__ of0, int* __restrict__ of1,
    int* __restrict__ cs0, int* __restrict__ cs1) {
    const unsigned* pairs = blockIdx.y ? pr1 : pr0;
    const int* boffs = blockIdx.y ? bo1 : bo0;
    int* offs = blockIdx.y ? of1 : of0;
    int* csr  = blockIdx.y ? cs1 : cs0;
    int b = blockIdx.x;
    int base = boffs[b];
    int n_e  = boffs[b + 1] - base;
    __shared__ int cnt[64], cur[64];
    int t = threadIdx.x;
    if (t < 64) cnt[t] = 0;
    __syncthreads();
    for (int i = t; i < n_e; i += 256) atomicAdd(&cnt[pairs[base + i] >> 20], 1);
    __syncthreads();
    if (t < 64) {   // wave 0: exclusive scan of 64 counts
        int x = cnt[t], v = x;
#pragma unroll
        for (int off = 1; off < 64; off <<= 1) {
            int u = __shfl_up(v, off, 64);
            if (t >= off) v += u;
        }
        cur[t] = v - x;
        int gn = b * 64 + t;
        if (gn < NN) offs[gn] = base + v - x;
    }
    __syncthreads();
    for (int i = t; i < n_e; i += 256) {
        unsigned pck = pairs[base + i];
        int dl = pck >> 20, sv = pck & 0xFFFFF;
        int pos = atomicAdd(&cur[dl], 1);
        csr[base + pos] = sv;
    }
}

// ---------------------------------------------------------------------------
// bf16 MFMA GEMM (generic, bf16 out, storage width 256):
// 128x128 tile, BK=32, 256 threads (4 waves 2x2), swizzled LDS, LDS epilogue.
// ---------------------------------------------------------------------------
__global__ __launch_bounds__(256) void mfma_gemm_kernel(
    const bf16* __restrict__ A, const bf16* __restrict__ Bt,
    const float* __restrict__ bias, bf16* __restrict__ out,
    int M, int K, int Nb, int do_relu) {
    __shared__ bf16 smem[16384];     // As | Bs during K-loop; epilogue buffer after
    bf16* As = smem;
    bf16* Bs = smem + 8192;

    const int t    = threadIdx.x;
    const int lane = t & 63;
    const int w    = t >> 6;
    const int row0 = blockIdx.y * 128;
    const int col0 = blockIdx.x * 128;

    f32x4 acc[4][4] = {};
    const int wm = (w >> 1) * 64, wn = (w & 1) * 64;
    const int fm = lane & 15, fC = lane >> 4;

    for (int k0 = 0; k0 < K; k0 += 32) {
#pragma unroll
        for (int r = 0; r < 2; r++) {
            int flat = r * 256 + t;
            int fr = flat >> 2, fc = flat & 3;
            int fcg = fc ^ ((fr >> 1) & 3);          // swizzle
            int arow = row0 + fr;
            if (arow > M - 1) arow = M - 1;
            gl_lds16(&A[(size_t)arow * K + k0 + fcg * 8], &As[flat * 8]);
        }
#pragma unroll
        for (int r = 0; r < 2; r++) {
            int flat = r * 256 + t;
            int fr = flat >> 2, fc = flat & 3;
            int fcg = fc ^ ((fr >> 1) & 3);
            int brow = col0 + fr;                    // Bt padded
            gl_lds16(&Bt[(size_t)brow * K + k0 + fcg * 8], &Bs[flat * 8]);
        }
        __syncthreads();

        bf16x8 af[4], bfr[4];
#pragma unroll
        for (int i = 0; i < 4; i++) af[i] = frag_ld(As, wm + i * 16 + fm, fC);
#pragma unroll
        for (int i = 0; i < 4; i++) bfr[i] = frag_ld(Bs, wn + i * 16 + fm, fC);
#pragma unroll
        for (int i = 0; i < 4; i++)
#pragma unroll
            for (int j = 0; j < 4; j++)
                acc[i][j] = __builtin_amdgcn_mfma_f32_16x16x32_bf16(af[i], bfr[j], acc[i][j], 0, 0, 0);
        __syncthreads();
    }

    float bv[4];
#pragma unroll
    for (int j = 0; j < 4; j++) {
        int col = col0 + wn + fm + j * 16;
        bv[j] = (bias && col < Nb) ? bias[col] : 0.f;
    }

#pragma unroll
    for (int p = 0; p < 2; p++) {
        if ((w >> 1) == p) {
#pragma unroll
            for (int i = 0; i < 4; i++)
#pragma unroll
                for (int j = 0; j < 4; j++)
#pragma unroll
                    for (int r2 = 0; r2 < 4; r2++) {
                        int rl = i * 16 + (lane >> 4) * 4 + r2;   // 0..63
                        int cl = wn + fm + j * 16;                // 0..127
                        float v = acc[i][j][r2] + bv[j];
                        if (do_relu) v = fmaxf(v, 0.f);
                        smem[rl * EPI_STRIDE + cl] = (bf16)v;
                    }
        }
        __syncthreads();
#pragma unroll
        for (int q = 0; q < 4; q++) {
            int flat = q * 256 + t;
            int rl = flat >> 4, seg = flat & 15;
            int grow = row0 + p * 64 + rl;
            if (grow < M)
                *(bf16x8*)&out[(size_t)grow * 256 + col0 + seg * 8] =
                    *(const bf16x8*)&smem[rl * EPI_STRIDE + seg * 8];
        }
        __syncthreads();
    }
}

// Fused W+Wr GEMM: Bt2 is 512x256. cols 0-255 -> out_lo (no act), cols 256-511 ->
// out_hi = relu(.+bias_hi). grid (4, ceil(M/128)).
__global__ __launch_bounds__(256) void mfma_gemm_fused_kernel(
    const bf16* __restrict__ A, const bf16* __restrict__ Bt2,
    const float* __restrict__ bias_hi,
    bf16* __restrict__ out_lo, bf16* __restrict__ out_hi, int M) {
    __shared__ bf16 smem[16384];
    bf16* As = smem;
    bf16* Bs = smem + 8192;

    const int t    = threadIdx.x;
    const int lane = t & 63;
    const int w    = t >> 6;
    const int row0 = blockIdx.y * 128;
    const int col0 = blockIdx.x * 128;   // 0..384

    f32x4 acc[4][4] = {};
    const int wm = (w >> 1) * 64, wn = (w & 1) * 64;
    const int fm = lane & 15, fC = lane >> 4;

    for (int k0 = 0; k0 < 256; k0 += 32) {
#pragma unroll
        for (int r = 0; r < 2; r++) {
            int flat = r * 256 + t;
            int fr = flat >> 2, fc = flat & 3;
            int fcg = fc ^ ((fr >> 1) & 3);
            int arow = row0 + fr;
            if (arow > M - 1) arow = M - 1;
            gl_lds16(&A[(size_t)arow * 256 + k0 + fcg * 8], &As[flat * 8]);
        }
#pragma unroll
        for (int r = 0; r < 2; r++) {
            int flat = r * 256 + t;
            int fr = flat >> 2, fc = flat & 3;
            int fcg = fc ^ ((fr >> 1) & 3);
            int brow = col0 + fr;
            gl_lds16(&Bt2[(size_t)brow * 256 + k0 + fcg * 8], &Bs[flat * 8]);
        }
        __syncthreads();

        bf16x8 af[4], bfr[4];
#pragma unroll
        for (int i = 0; i < 4; i++) af[i] = frag_ld(As, wm + i * 16 + fm, fC);
#pragma unroll
        for (int i = 0; i < 4; i++) bfr[i] = frag_ld(Bs, wn + i * 16 + fm, fC);
#pragma unroll
        for (int i = 0; i < 4; i++)
#pragma unroll
            for (int j = 0; j < 4; j++)
                acc[i][j] = __builtin_amdgcn_mfma_f32_16x16x32_bf16(af[i], bfr[j], acc[i][j], 0, 0, 0);
        __syncthreads();
    }

    const bool hi = (col0 >= 256);          // block-uniform
    bf16* out = hi ? out_hi : out_lo;
    const int cb = hi ? col0 - 256 : col0;

    float bv[4];
#pragma unroll
    for (int j = 0; j < 4; j++) {
        int col = cb + wn + fm + j * 16;
        bv[j] = hi ? bias_hi[col] : 0.f;
    }

#pragma unroll
    for (int p = 0; p < 2; p++) {
        if ((w >> 1) == p) {
#pragma unroll
            for (int i = 0; i < 4; i++)
#pragma unroll
                for (int j = 0; j < 4; j++)
#pragma unroll
                    for (int r2 = 0; r2 < 4; r2++) {
                        int rl = i * 16 + (lane >> 4) * 4 + r2;
                        int cl = wn + fm + j * 16;
                        float v = acc[i][j][r2] + bv[j];
                        if (hi) v = fmaxf(v, 0.f);
                        smem[rl * EPI_STRIDE + cl] = (bf16)v;
                    }
        }
        __syncthreads();
#pragma unroll
        for (int q = 0; q < 4; q++) {
            int flat = q * 256 + t;
            int rl = flat >> 4, seg = flat & 15;
            int grow = row0 + p * 64 + rl;
            if (grow < M)
                *(bf16x8*)&out[(size_t)grow * 256 + cb + seg * 8] =
                    *(const bf16x8*)&smem[rl * EPI_STRIDE + seg * 8];
        }
        __syncthreads();
    }
}

// ---------------------------------------------------------------------------
// edge aggregation + combine (bf16 in/out, fp32 accumulate):
// H[v] = relu(sum_{e: dst=v} hW[src[e]] + b) + res[v]
// one wave per dst node; lane covers 8 feats (16B), half-waves cover 2 edges.
// ---------------------------------------------------------------------------
__global__ __launch_bounds__(256) void agg_combine_kernel(const bf16* __restrict__ hW,
                                                          const int* __restrict__ csr_src,
                                                          const int* __restrict__ offsets,
                                                          const float* __restrict__ bias,
                                                          const bf16* __restrict__ res,
                                                          bf16* __restrict__ H, int n_nodes) {
    int wave = threadIdx.x >> 6;
    int lane = threadIdx.x & 63;
    int node = blockIdx.x * 4 + wave;
    if (node >= n_nodes) return;
    int beg = offsets[node], end = offsets[node + 1];
    const int half = lane >> 5;
    const int fo   = (lane & 31) * 8;

    float acc[8] = {};
    int j = beg;
    for (; j + 2 + half < end; j += 4) {
        int s0 = csr_src[j + half];
        int s1 = csr_src[j + 2 + half];
        bf16x8 v0 = *(const bf16x8*)&hW[(size_t)s0 * DD + fo];
        bf16x8 v1 = *(const bf16x8*)&hW[(size_t)s1 * DD + fo];
#pragma unroll
        for (int q = 0; q < 8; q++) acc[q] += (float)v0[q];
#pragma unroll
        for (int q = 0; q < 8; q++) acc[q] += (float)v1[q];
    }
    for (; j + half < end; j += 2) {
        int s = csr_src[j + half];
        bf16x8 v = *(const bf16x8*)&hW[(size_t)s * DD + fo];
#pragma unroll
        for (int q = 0; q < 8; q++) acc[q] += (float)v[q];
    }
#pragma unroll
    for (int q = 0; q < 8; q++) acc[q] += __shfl_xor(acc[q], 32, 64);

    if (half == 0) {
        float4 b0 = *(const float4*)&bias[fo];
        float4 b1 = *(const float4*)&bias[fo + 4];
        bf16x8 rv = *(const bf16x8*)&res[(size_t)node * DD + fo];
        bf16x8 o;
        o[0] = (bf16)(fmaxf(acc[0] + b0.x, 0.f) + (float)rv[0]);
        o[1] = (bf16)(fmaxf(acc[1] + b0.y, 0.f) + (float)rv[1]);
        o[2] = (bf16)(fmaxf(acc[2] + b0.z, 0.f) + (float)rv[2]);
        o[3] = (bf16)(fmaxf(acc[3] + b0.w, 0.f) + (float)rv[3]);
        o[4] = (bf16)(fmaxf(acc[4] + b1.x, 0.f) + (float)rv[4]);
        o[5] = (bf16)(fmaxf(acc[5] + b1.y, 0.f) + (float)rv[5]);
        o[6] = (bf16)(fmaxf(acc[6] + b1.z, 0.f) + (float)rv[6]);
        o[7] = (bf16)(fmaxf(acc[7] + b1.w, 0.f) + (float)rv[7]);
        *(bf16x8*)&H[(size_t)node * DD + fo] = o;
    }
}

// ---------------------------------------------------------------------------
// per-graph segment sum of P[N_nodes, 256(stride)] bf16, cols<GFEAT; block per graph
// ---------------------------------------------------------------------------
__global__ __launch_bounds__(256) void graph_reduce_kernel(const bf16* __restrict__ P,
                                                           const int* __restrict__ gids,
                                                           float* __restrict__ G, int n_nodes) {
    int g = blockIdx.x;
    int lo = 0, hi = n_nodes;
    while (lo < hi) { int mid = (lo + hi) >> 1; if (gids[mid] < g) lo = mid + 1; else hi = mid; }
    int beg = lo;
    hi = n_nodes;
    while (lo < hi) { int mid = (lo + hi) >> 1; if (gids[mid] < g + 1) lo = mid + 1; else hi = mid; }
    int end = lo;

    int c = threadIdx.x;
    if (c < GFEAT) {
        float acc = 0.f;
        for (int r = beg; r < end; r++) acc += (float)P[(size_t)r * 256 + c];
        G[(size_t)g * GFEAT + c] = acc;
    }
}

__global__ __launch_bounds__(256) void predictor_kernel(const float* __restrict__ G1,
                                                        const float* __restrict__ G2,
                                                        const float* __restrict__ Wp,
                                                        const float* __restrict__ bp,
                                                        float* __restrict__ out) {
    int i = blockIdx.x * 256 + threadIdx.x;
    if (i >= NG) return;
    float acc = bp[0];
    for (int f = 0; f < GFEAT; f++)
        acc += (G1[i * GFEAT + f] + G2[i * GFEAT + f]) * Wp[f];
    out[i] = acc;
}

// ---------------------------------------------------------------------------
// host-side branch driver (CSR already built)
// ---------------------------------------------------------------------------
static void run_branch(const bf16* Xb, const int* gids,
                       const bf16* WWr, const float* b, const float* br,
                       const bf16* Rit, const float* rbi, const bf16* Rot, const float* rbo,
                       float* Gout, bf16* hWb, bf16* resb, bf16* Hb, bf16* P,
                       const int* offs, const int* csr, hipStream_t stream) {
    dim3 gf(4, (NN + 127) / 128);
    dim3 g2(2, (NN + 127) / 128);
    mfma_gemm_fused_kernel<<<gf, 256, 0, stream>>>(Xb, WWr, br, hWb, resb, NN);
    agg_combine_kernel<<<(NN + 3) / 4, 256, 0, stream>>>(hWb, csr, offs, b, resb, Hb, NN);
    mfma_gemm_kernel<<<g2, 256, 0, stream>>>(Hb, Rit, rbi, hWb, NN, DD, DD, 1);
    mfma_gemm_kernel<<<g2, 256, 0, stream>>>(hWb, Rot, rbo, P, NN, DD, GFEAT, 0);
    graph_reduce_kernel<<<NG, 256, 0, stream>>>(P, gids, Gout, NN);
}

extern "C" void kernel_launch(void* const* d_in, const int* in_sizes, int n_in,
                              void* d_out, int out_size, void* d_ws, size_t ws_size,
                              hipStream_t stream) {
    const float* X1   = (const float*)d_in[0];
    const float* X2   = (const float*)d_in[2];
    const int*   src1 = (const int*)d_in[4];
    const int*   dst1 = (const int*)d_in[5];
    const int*   gid1 = (const int*)d_in[6];
    const int*   src2 = (const int*)d_in[7];
    const int*   dst2 = (const int*)d_in[8];
    const int*   gid2 = (const int*)d_in[9];
    const float* W1  = (const float*)d_in[10]; const float* b1  = (const float*)d_in[11];
    const float* Wr1 = (const float*)d_in[12]; const float* br1 = (const float*)d_in[13];
    const float* W2  = (const float*)d_in[14]; const float* b2  = (const float*)d_in[15];
    const float* Wr2 = (const float*)d_in[16]; const float* br2 = (const float*)d_in[17];
    const float* Ri1 = (const float*)d_in[18]; const float* rbi1 = (const float*)d_in[19];
    const float* Ro1 = (const float*)d_in[20]; const float* rbo1 = (const float*)d_in[21];
    const float* Ri2 = (const float*)d_in[22]; const float* rbi2 = (const float*)d_in[23];
    const float* Ro2 = (const float*)d_in[24]; const float* rbo2 = (const float*)d_in[25];
    const float* Wp  = (const float*)d_in[26]; const float* bp  = (const float*)d_in[27];

    // workspace layout
    char* p = (char*)d_ws;
    bf16* Xb1  = (bf16*)p; p += (size_t)NN * DD * sizeof(bf16);
    bf16* Xb2  = (bf16*)p; p += (size_t)NN * DD * sizeof(bf16);
    bf16* hWb  = (bf16*)p; p += (size_t)NN * DD * sizeof(bf16);
    bf16* resb = (bf16*)p; p += (size_t)NN * DD * sizeof(bf16);
    bf16* Hb   = (bf16*)p; p += (size_t)NN * DD * sizeof(bf16);
    bf16* P    = (bf16*)p; p += (size_t)NN * 256 * sizeof(bf16);
    float* G1  = (float*)p; p += (size_t)NG * GFEAT * sizeof(float);
    float* G2  = (float*)p; p += (size_t)NG * GFEAT * sizeof(float);
    bf16* Wbase = (bf16*)p; p += 8 * 65536 * sizeof(bf16);
    int* offs1  = (int*)p; p += (NN + 1) * sizeof(int);
    int* offs2  = (int*)p; p += (NN + 1) * sizeof(int);
    int* bcnt1  = (int*)p; p += NBK * sizeof(int);
    int* bcnt2  = (int*)p; p += NBK * sizeof(int);
    int* boffs1 = (int*)p; p += (NBK + 1) * sizeof(int);
    int* boffs2 = (int*)p; p += (NBK + 1) * sizeof(int);
    int* bcur1  = (int*)p; p += NBK * sizeof(int);
    int* bcur2  = (int*)p; p += NBK * sizeof(int);
    int* csr1   = (int*)p; p += NE * sizeof(int);
    int* csr2   = (int*)p;
    // pairs alias the P buffer: all CSR-build work precedes the first write of P
    unsigned* pairs1 = (unsigned*)P;
    unsigned* pairs2 = pairs1 + NE;

    conv_w8_kernel<<<dim3(256, 8), 256, 0, stream>>>(W1, Wr1, Ri1, Ro1, W2, Wr2, Ri2, Ro2, Wbase);
    conv_x2_kernel<<<dim3((NN * DD / 4 + 255) / 256, 2), 256, 0, stream>>>(
        X1, X2, Xb1, Xb2, NN * DD / 4);

    // bucketed CSR build for both branches
    zero_small2_kernel<<<1, 1024, 0, stream>>>(bcnt1, bcnt2, NBK);
    bucket_hist2_kernel<<<dim3((NE + 2047) / 2048, 2), 256, 0, stream>>>(dst1, dst2, bcnt1, bcnt2, NE);
    bucket_scan2_kernel<<<dim3(1, 2), 1024, 0, stream>>>(bcnt1, bcnt2, boffs1, boffs2,
                                                         bcur1, bcur2, &offs1[NN], &offs2[NN]);
    bucket_append2_kernel<<<dim3((NE + 255) / 256, 2), 256, 0, stream>>>(
        src1, src2, dst1, dst2, bcur1, bcur2, pairs1, pairs2, NE);
    fine_scatter2_kernel<<<dim3(NBK, 2), 256, 0, stream>>>(pairs1, pairs2, boffs1, boffs2,
                                                           offs1, offs2, csr1, csr2);

    run_branch(Xb1, gid1, Wbase + 0 * 65536, b1, br1,
               Wbase + 2 * 65536, rbi1, Wbase + 3 * 65536, rbo1,
               G1, hWb, resb, Hb, P, offs1, csr1, stream);
    run_branch(Xb2, gid2, Wbase + 4 * 65536, b2, br2,
               Wbase + 6 * 65536, rbi2, Wbase + 7 * 65536, rbo2,
               G2, hWb, resb, Hb, P, offs2, csr2, stream);

    predictor_kernel<<<(NG + 255) / 256, 256, 0, stream>>>(G1, G2, Wp, bp, (float*)d_out);
}